// Round 1
// baseline (337.516 us; speedup 1.0000x reference)
//
#include <hip/hip_runtime.h>
#include <math.h>

// spu(z) = z^2 - 0.5            for z >= 0
//        = sigmoid(-z) - 1      for z < 0
__device__ __forceinline__ float spu_f(float z) {
    // sigmoid(-z) = 1 / (1 + exp(z))
    float s = 1.0f / (1.0f + expf(z));
    return (z >= 0.0f) ? (z * z - 0.5f) : (s - 1.0f);
}

__device__ __forceinline__ float dspu_f(float z) {
    float s = 1.0f / (1.0f + expf(z));       // sigmoid(-z)
    return (z >= 0.0f) ? (2.0f * z) : (-s * (1.0f - s));
}

__device__ __forceinline__ void spu_elem(float x, float l, float u,
                                         float& xo, float& lo, float& uo) {
    // p = clip(u - (|l| + |u|)/2, l, u)
    float p = u - (fabsf(l) + fabsf(u)) * 0.5f;
    p = fminf(fmaxf(p, l), u);

    float sl = spu_f(l);
    float su = spu_f(u);
    float sp = spu_f(p);

    // chord through (l, sl) and (u, su)
    float chord_slope = (su - sl) / ((u != l) ? (u - l) : 1.0f);
    float chord_int   = sl - chord_slope * l;
    // tangent at p
    float tan_slope = dspu_f(p);
    float tan_int   = sp - p * tan_slope;
    // line through (l, sl) and (0, -0.5)
    float zl_slope = (-0.5f - sl) / ((l != 0.0f) ? (-l) : 1.0f);
    float zl_int   = -0.5f;

    bool upos = (u > 0.0f);
    bool ppos = (p >= 0.0f);

    float lb_slope = upos ? (ppos ? tan_slope : zl_slope) : chord_slope;
    float lb_int   = upos ? (ppos ? tan_int   : zl_int  ) : chord_int;
    float ub_slope = upos ? chord_slope : tan_slope;
    float ub_int   = upos ? chord_int   : tan_int;

    lo = lb_int + ((lb_slope > 0.0f) ? l : u) * lb_slope;
    uo = ub_int + ((ub_slope > 0.0f) ? u : l) * ub_slope;
    xo = spu_f(x);
}

__global__ __launch_bounds__(256) void spu_transformer_kernel(
    const float* __restrict__ x,
    const float* __restrict__ l,
    const float* __restrict__ u,
    float* __restrict__ xo,
    float* __restrict__ lo,
    float* __restrict__ uo,
    int n)
{
    int i4 = blockIdx.x * blockDim.x + threadIdx.x;
    int n4 = n >> 2;

    if (i4 < n4) {
        float4 xv = ((const float4*)x)[i4];
        float4 lv = ((const float4*)l)[i4];
        float4 uv = ((const float4*)u)[i4];
        float4 xov, lov, uov;
        spu_elem(xv.x, lv.x, uv.x, xov.x, lov.x, uov.x);
        spu_elem(xv.y, lv.y, uv.y, xov.y, lov.y, uov.y);
        spu_elem(xv.z, lv.z, uv.z, xov.z, lov.z, uov.z);
        spu_elem(xv.w, lv.w, uv.w, xov.w, lov.w, uov.w);
        ((float4*)xo)[i4] = xov;
        ((float4*)lo)[i4] = lov;
        ((float4*)uo)[i4] = uov;
    }

    // scalar tail (n % 4 != 0 safety; no-op for n = 16M)
    int tail_start = n4 << 2;
    int ti = tail_start + i4;
    if (i4 < (n - tail_start)) {
        float xs, ls, us;
        spu_elem(x[ti], l[ti], u[ti], xs, ls, us);
        xo[ti] = xs;
        lo[ti] = ls;
        uo[ti] = us;
    }
}

extern "C" void kernel_launch(void* const* d_in, const int* in_sizes, int n_in,
                              void* d_out, int out_size, void* d_ws, size_t ws_size,
                              hipStream_t stream) {
    const float* x = (const float*)d_in[0];
    const float* l = (const float*)d_in[1];
    const float* u = (const float*)d_in[2];
    int n = in_sizes[0];

    float* xo = (float*)d_out;          // x_out
    float* lo = (float*)d_out + n;      // l_out
    float* uo = (float*)d_out + 2 * n;  // u_out

    int n4 = (n + 3) >> 2;
    int block = 256;
    int grid = (n4 + block - 1) / block;
    spu_transformer_kernel<<<grid, block, 0, stream>>>(x, l, u, xo, lo, uo, n);
}

// Round 2
// 334.071 us; speedup vs baseline: 1.0103x; 1.0103x over previous
//
#include <hip/hip_runtime.h>
#include <math.h>

#define LOG2E 1.44269504088896340736f

// Fast sigmoid(-z) = 1 / (1 + exp(z)) using native v_exp_f32 / v_rcp_f32.
// v_exp_f32 handles overflow: z large + -> exp2 -> inf -> rcp -> 0 (correct);
// z large - -> 0 -> rcp(1) = 1 (correct).
__device__ __forceinline__ float sigm_neg(float z) {
    float e = __builtin_amdgcn_exp2f(z * LOG2E);
    return __builtin_amdgcn_rcpf(1.0f + e);
}

__device__ __forceinline__ float rcp_fast(float z) {
    return __builtin_amdgcn_rcpf(z);
}

// spu(z) = z^2 - 0.5 (z>=0) | sigmoid(-z) - 1 (z<0), with sigmoid given
__device__ __forceinline__ float spu_from_sig(float z, float s) {
    return (z >= 0.0f) ? (z * z - 0.5f) : (s - 1.0f);
}

__device__ __forceinline__ void spu_elem(float x, float l, float u,
                                         float& xo, float& lo, float& uo) {
    // p = clip(u - (|l| + |u|)/2, l, u)
    float p = u - (fabsf(l) + fabsf(u)) * 0.5f;
    p = fminf(fmaxf(p, l), u);

    // 4 native exps total (l, u, p, x); sigmoid of p shared by spu & dspu
    float sig_l = sigm_neg(l);
    float sig_u = sigm_neg(u);
    float sig_p = sigm_neg(p);
    float sig_x = sigm_neg(x);

    float sl = spu_from_sig(l, sig_l);
    float su = spu_from_sig(u, sig_u);
    float sp = spu_from_sig(p, sig_p);

    // chord through (l, sl) and (u, su)
    float chord_slope = (su - sl) * rcp_fast((u != l) ? (u - l) : 1.0f);
    float chord_int   = sl - chord_slope * l;
    // tangent at p: dspu(p) = 2p (p>=0) | -s(1-s) (p<0)
    float tan_slope = (p >= 0.0f) ? (2.0f * p) : (-sig_p * (1.0f - sig_p));
    float tan_int   = sp - p * tan_slope;
    // line through (l, sl) and (0, -0.5)
    float zl_slope = (-0.5f - sl) * rcp_fast((l != 0.0f) ? (-l) : 1.0f);
    float zl_int   = -0.5f;

    bool upos = (u > 0.0f);
    bool ppos = (p >= 0.0f);

    float lb_slope = upos ? (ppos ? tan_slope : zl_slope) : chord_slope;
    float lb_int   = upos ? (ppos ? tan_int   : zl_int  ) : chord_int;
    float ub_slope = upos ? chord_slope : tan_slope;
    float ub_int   = upos ? chord_int   : tan_int;

    lo = lb_int + ((lb_slope > 0.0f) ? l : u) * lb_slope;
    uo = ub_int + ((ub_slope > 0.0f) ? u : l) * ub_slope;
    xo = spu_from_sig(x, sig_x);
}

__global__ __launch_bounds__(256) void spu_transformer_kernel(
    const float* __restrict__ x,
    const float* __restrict__ l,
    const float* __restrict__ u,
    float* __restrict__ xo,
    float* __restrict__ lo,
    float* __restrict__ uo,
    int n)
{
    int i4 = blockIdx.x * blockDim.x + threadIdx.x;
    int n4 = n >> 2;

    if (i4 < n4) {
        float4 xv = ((const float4*)x)[i4];
        float4 lv = ((const float4*)l)[i4];
        float4 uv = ((const float4*)u)[i4];
        float4 xov, lov, uov;
        spu_elem(xv.x, lv.x, uv.x, xov.x, lov.x, uov.x);
        spu_elem(xv.y, lv.y, uv.y, xov.y, lov.y, uov.y);
        spu_elem(xv.z, lv.z, uv.z, xov.z, lov.z, uov.z);
        spu_elem(xv.w, lv.w, uv.w, xov.w, lov.w, uov.w);
        ((float4*)xo)[i4] = xov;
        ((float4*)lo)[i4] = lov;
        ((float4*)uo)[i4] = uov;
    }

    // scalar tail (n % 4 != 0 safety; no-op for n = 16M)
    int tail_start = n4 << 2;
    int ti = tail_start + i4;
    if (i4 < (n - tail_start)) {
        float xs, ls, us;
        spu_elem(x[ti], l[ti], u[ti], xs, ls, us);
        xo[ti] = xs;
        lo[ti] = ls;
        uo[ti] = us;
    }
}

extern "C" void kernel_launch(void* const* d_in, const int* in_sizes, int n_in,
                              void* d_out, int out_size, void* d_ws, size_t ws_size,
                              hipStream_t stream) {
    const float* x = (const float*)d_in[0];
    const float* l = (const float*)d_in[1];
    const float* u = (const float*)d_in[2];
    int n = in_sizes[0];

    float* xo = (float*)d_out;          // x_out
    float* lo = (float*)d_out + n;      // l_out
    float* uo = (float*)d_out + 2 * n;  // u_out

    int n4 = (n + 3) >> 2;
    int block = 256;
    int grid = (n4 + block - 1) / block;
    spu_transformer_kernel<<<grid, block, 0, stream>>>(x, l, u, xo, lo, uo, n);
}